// Round 1
// baseline (219.930 us; speedup 1.0000x reference)
//
#include <hip/hip_runtime.h>

#define LAMBDA_COORD 5.0f
#define LAMBDA_NOOBJ 0.5f
#define WH_EPS 1e-6f
#define IOU_EPS 1e-6f

// IOU between box a (cx,cy,w,h) and b (cx,cy,w,h), matching _iou_yolo exactly.
__device__ __forceinline__ float iou_yolo(float a0, float a1, float a2, float a3,
                                          float b0, float b1, float b2, float b3) {
    float ax1 = a0 - a2 * 0.5f, ay1 = a1 - a3 * 0.5f;
    float ax2 = a0 + a2 * 0.5f, ay2 = a1 + a3 * 0.5f;
    float bx1 = b0 - b2 * 0.5f, by1 = b1 - b3 * 0.5f;
    float bx2 = b0 + b2 * 0.5f, by2 = b1 + b3 * 0.5f;
    float iw = fmaxf(fminf(ax2, bx2) - fmaxf(ax1, bx1), 0.0f);
    float ih = fmaxf(fminf(ay2, by2) - fmaxf(ay1, by1), 0.0f);
    float inter = iw * ih;
    float area_a = fabsf((ax2 - ax1) * (ay2 - ay1));
    float area_b = fabsf((bx2 - bx1) * (by2 - by1));
    return inter / (area_a + area_b - inter + IOU_EPS);
}

// Loss for one S*S cell: t, p point at 30 consecutive floats (constant offsets
// after inlining -> stays in registers).
__device__ __forceinline__ float cell_loss(const float* __restrict__ t,
                                           const float* __restrict__ p) {
    const float b0 = t[0], b1 = t[1], b2 = t[2], b3 = t[3], t4 = t[4];

    float iou1 = iou_yolo(b0, b1, b2, b3, p[0], p[1], p[2], p[3]);
    float iou2 = iou_yolo(b0, b1, b2, b3, p[5], p[6], p[7], p[8]);
    bool use1 = iou1 > iou2;

    float bh0 = use1 ? p[0] : p[5];
    float bh1 = use1 ? p[1] : p[6];
    float bh2 = use1 ? p[2] : p[7];
    float bh3 = use1 ? p[3] : p[8];
    float conf_c = use1 ? p[4] : p[9];
    float conf_o = use1 ? p[9] : p[4];

    float dx = b0 - bh0, dy = b1 - bh1;
    float xy = LAMBDA_COORD * (dx * dx + dy * dy);

    float sw = sqrtf(b2) - sqrtf(fabsf(bh2 + WH_EPS));
    float sh = sqrtf(b3) - sqrtf(fabsf(bh3 + WH_EPS));
    float wh = LAMBDA_COORD * (sw * sw + sh * sh);

    float dc = t4 - conf_c;
    float obj_conf = dc * dc;
    float noobj_in_obj = LAMBDA_NOOBJ * conf_o * conf_o;

    float cls = 0.0f;
#pragma unroll
    for (int k = 10; k < 30; ++k) {
        float d = t[k] - p[k];
        cls += d * d;
    }

    float obj_terms = xy + wh + obj_conf + noobj_in_obj + cls;

    float d4 = t4 - p[4], d9 = t4 - p[9];
    float noobj_terms = LAMBDA_NOOBJ * (d4 * d4 + d9 * d9);

    return (t4 == 1.0f) ? obj_terms : noobj_terms;
}

// One thread per PAIR of cells: 2*30 floats = 240 B is 16B-aligned -> float4.
__global__ __launch_bounds__(256) void yolo_loss_kernel(
    const float* __restrict__ t_g, const float* __restrict__ p_g,
    float* __restrict__ out, int n_pairs, float inv_batch) {
    int pp = blockIdx.x * blockDim.x + threadIdx.x;

    float v = 0.0f;
    if (pp < n_pairs) {
        const float4* tv = (const float4*)t_g + (size_t)pp * 15;
        const float4* pv = (const float4*)p_g + (size_t)pp * 15;
        float t[60], p[60];
#pragma unroll
        for (int i = 0; i < 15; ++i) {
            float4 a = tv[i];
            t[4 * i + 0] = a.x; t[4 * i + 1] = a.y;
            t[4 * i + 2] = a.z; t[4 * i + 3] = a.w;
            float4 b = pv[i];
            p[4 * i + 0] = b.x; p[4 * i + 1] = b.y;
            p[4 * i + 2] = b.z; p[4 * i + 3] = b.w;
        }
        v = cell_loss(t, p) + cell_loss(t + 30, p + 30);
    }

    // wave64 reduction
#pragma unroll
    for (int off = 32; off > 0; off >>= 1)
        v += __shfl_down(v, off, 64);

    __shared__ float smem[4];  // 256 threads / 64 = 4 waves
    int lane = threadIdx.x & 63;
    int wid = threadIdx.x >> 6;
    if (lane == 0) smem[wid] = v;
    __syncthreads();
    if (threadIdx.x == 0) {
        float s = smem[0] + smem[1] + smem[2] + smem[3];
        atomicAdd(out, s * inv_batch);
    }
}

extern "C" void kernel_launch(void* const* d_in, const int* in_sizes, int n_in,
                              void* d_out, int out_size, void* d_ws, size_t ws_size,
                              hipStream_t stream) {
    const float* t = (const float*)d_in[0];  // y_trues
    const float* p = (const float*)d_in[1];  // y_preds
    float* out = (float*)d_out;

    const int total = in_sizes[0];       // BATCH*S*S*D = 24,084,480
    const int cells = total / 30;        // 802,816
    const int pairs = cells / 2;         // 401,408
    const int batch = cells / 49;        // 16,384
    const float inv_batch = 1.0f / (float)batch;

    // d_out is poisoned (0xAA) before every replay — zero it on-stream.
    hipMemsetAsync(out, 0, sizeof(float), stream);

    const int block = 256;
    const int grid = (pairs + block - 1) / block;
    yolo_loss_kernel<<<grid, block, 0, stream>>>(t, p, out, pairs, inv_batch);
}

// Round 2
// 207.766 us; speedup vs baseline: 1.0585x; 1.0585x over previous
//
#include <hip/hip_runtime.h>

#define LAMBDA_COORD 5.0f
#define LAMBDA_NOOBJ 0.5f
#define WH_EPS 1e-6f
#define IOU_EPS 1e-6f

// IOU between box a (cx,cy,w,h) and b (cx,cy,w,h), matching _iou_yolo exactly.
__device__ __forceinline__ float iou_yolo(float a0, float a1, float a2, float a3,
                                          float b0, float b1, float b2, float b3) {
    float ax1 = a0 - a2 * 0.5f, ay1 = a1 - a3 * 0.5f;
    float ax2 = a0 + a2 * 0.5f, ay2 = a1 + a3 * 0.5f;
    float bx1 = b0 - b2 * 0.5f, by1 = b1 - b3 * 0.5f;
    float bx2 = b0 + b2 * 0.5f, by2 = b1 + b3 * 0.5f;
    float iw = fmaxf(fminf(ax2, bx2) - fmaxf(ax1, bx1), 0.0f);
    float ih = fmaxf(fminf(ay2, by2) - fmaxf(ay1, by1), 0.0f);
    float inter = iw * ih;
    float area_a = fabsf((ax2 - ax1) * (ay2 - ay1));
    float area_b = fabsf((bx2 - bx1) * (by2 - by1));
    return inter / (area_a + area_b - inter + IOU_EPS);
}

// Loss for one S*S cell; t/p point at 30 consecutive floats in LDS.
__device__ __forceinline__ float cell_loss(const float* t, const float* p) {
    const float b0 = t[0], b1 = t[1], b2 = t[2], b3 = t[3], t4 = t[4];

    float iou1 = iou_yolo(b0, b1, b2, b3, p[0], p[1], p[2], p[3]);
    float iou2 = iou_yolo(b0, b1, b2, b3, p[5], p[6], p[7], p[8]);
    bool use1 = iou1 > iou2;

    float bh0 = use1 ? p[0] : p[5];
    float bh1 = use1 ? p[1] : p[6];
    float bh2 = use1 ? p[2] : p[7];
    float bh3 = use1 ? p[3] : p[8];
    float conf_c = use1 ? p[4] : p[9];
    float conf_o = use1 ? p[9] : p[4];

    float dx = b0 - bh0, dy = b1 - bh1;
    float xy = LAMBDA_COORD * (dx * dx + dy * dy);

    float sw = sqrtf(b2) - sqrtf(fabsf(bh2 + WH_EPS));
    float sh = sqrtf(b3) - sqrtf(fabsf(bh3 + WH_EPS));
    float wh = LAMBDA_COORD * (sw * sw + sh * sh);

    float dc = t4 - conf_c;
    float obj_conf = dc * dc;
    float noobj_in_obj = LAMBDA_NOOBJ * conf_o * conf_o;

    float cls = 0.0f;
#pragma unroll
    for (int k = 10; k < 30; ++k) {
        float d = t[k] - p[k];
        cls += d * d;
    }

    float obj_terms = xy + wh + obj_conf + noobj_in_obj + cls;

    float d4 = t4 - p[4], d9 = t4 - p[9];
    float noobj_terms = LAMBDA_NOOBJ * (d4 * d4 + d9 * d9);

    return (t4 == 1.0f) ? obj_terms : noobj_terms;
}

// Block = 256 threads, 256 cells. Stage both inputs' contiguous 30,720 B
// chunks into LDS with lane-contiguous float4 loads (true coalescing),
// then each thread computes one cell's loss from LDS.
// LDS = 61,440 B -> 2 blocks/CU (8 waves/CU); each thread has ~16 dwordx4
// in flight during staging, which is plenty of MLP for the HBM stream.
constexpr int CELLS = 256;              // cells per block
constexpr int CFLOATS = CELLS * 30;     // 7680 floats per array per block
constexpr int CVEC4 = CFLOATS / 4;      // 1920 float4 per array per block
constexpr int NITER = CVEC4 / 256;      // 7 full rounds (+ half round)

__global__ __launch_bounds__(256) void yolo_loss_kernel(
    const float* __restrict__ t_g, const float* __restrict__ p_g,
    float* __restrict__ out, float inv_batch) {
    __shared__ float st[CFLOATS];
    __shared__ float sp[CFLOATS];
    __shared__ float swave[4];

    const int tid = threadIdx.x;
    const size_t base4 = (size_t)blockIdx.x * CVEC4;  // float4 index of chunk
    const float4* tg = (const float4*)t_g + base4;
    const float4* pg = (const float4*)p_g + base4;
    float4* st4 = (float4*)st;
    float4* sp4 = (float4*)sp;

    // Coalesced staging: lane-contiguous float4s. 1920 = 7.5 * 256.
#pragma unroll
    for (int j = 0; j < NITER; ++j) {
        int i = tid + j * 256;
        st4[i] = tg[i];
        sp4[i] = pg[i];
    }
    {
        int i = tid + NITER * 256;
        if (i < CVEC4) {
            st4[i] = tg[i];
            sp4[i] = pg[i];
        }
    }
    __syncthreads();

    // Compute: thread tid owns cell tid. LDS stride 30 floats -> 2-way bank
    // aliasing only (gcd(30,32)=2), which is free on gfx950.
    float v = cell_loss(st + tid * 30, sp + tid * 30);

    // wave64 reduction
#pragma unroll
    for (int off = 32; off > 0; off >>= 1)
        v += __shfl_down(v, off, 64);

    int lane = tid & 63;
    int wid = tid >> 6;
    if (lane == 0) swave[wid] = v;
    __syncthreads();
    if (tid == 0) {
        float s = swave[0] + swave[1] + swave[2] + swave[3];
        atomicAdd(out, s * inv_batch);
    }
}

extern "C" void kernel_launch(void* const* d_in, const int* in_sizes, int n_in,
                              void* d_out, int out_size, void* d_ws, size_t ws_size,
                              hipStream_t stream) {
    const float* t = (const float*)d_in[0];  // y_trues
    const float* p = (const float*)d_in[1];  // y_preds
    float* out = (float*)d_out;

    const int total = in_sizes[0];       // BATCH*S*S*D = 24,084,480
    const int cells = total / 30;        // 802,816
    const int batch = cells / 49;        // 16,384
    const float inv_batch = 1.0f / (float)batch;

    // d_out is poisoned (0xAA) before every replay — zero it on-stream.
    hipMemsetAsync(out, 0, sizeof(float), stream);

    const int grid = cells / CELLS;      // 3136 blocks, exact (802816 = 3136*256)
    yolo_loss_kernel<<<grid, 256, 0, stream>>>(t, p, out, inv_batch);
}